// Round 1
// baseline (498.956 us; speedup 1.0000x reference)
//
#include <hip/hip_runtime.h>
#include <hip/hip_bf16.h>
#include <stdint.h>

#define N_NODES 100000
#define N_RELS  8
#define N_EDGES 150000
#define D_IN    128
#define D_OUT   128
#define KCOLS   1152   // 8*128 relation cols + 128 self-loop cols
#define CAP     64     // per-dst edge bucket capacity (avg combined deg = 12)

typedef short bf16x8 __attribute__((ext_vector_type(8)));
typedef float f32x4  __attribute__((ext_vector_type(4)));

__device__ __forceinline__ unsigned short f2b(float f) {
    union { float f; unsigned u; } v; v.f = f;
    unsigned r = v.u + 0x7FFF + ((v.u >> 16) & 1);   // RNE
    return (unsigned short)(r >> 16);
}
__device__ __forceinline__ float b2f(unsigned short h) {
    union { unsigned u; float f; } v; v.u = ((unsigned)h) << 16;
    return v.f;
}

// ---------------------------------------------------------------------------
// Pre-transpose concatenated weights into BT[col][k] bf16, col in [0,1152)
// col < 1024: rel r = col>>7, out o = col&127 -> weight[r, k, o]
// col >= 1024: self_loop_weight[k, col-1024]
// ---------------------------------------------------------------------------
__global__ void prep_w(const float* __restrict__ W, const float* __restrict__ Wself,
                       unsigned short* __restrict__ BT) {
    int tid = blockIdx.x * 256 + threadIdx.x;
    if (tid >= KCOLS * 128) return;
    int col = tid >> 7, k = tid & 127;
    float v;
    if (col < 1024) {
        int r = col >> 7, o = col & 127;
        v = W[(r << 14) + (k << 7) + o];
    } else {
        v = Wself[(k << 7) + (col - 1024)];
    }
    BT[tid] = f2b(v);
}

// ---------------------------------------------------------------------------
// Per-edge: per-(rel,dst) degree histogram + scatter edge into per-dst bucket
// rec packs (r<<17)|src  (src < 2^17)
// ---------------------------------------------------------------------------
__global__ void edge_build(const int* __restrict__ src, const int* __restrict__ dst,
                           int* __restrict__ deg, int* __restrict__ cnt,
                           int* __restrict__ ebuf) {
    int e = blockIdx.x * 256 + threadIdx.x;
    int r = blockIdx.y;
    if (e >= N_EDGES) return;
    int s = src[r * N_EDGES + e];
    int d = dst[r * N_EDGES + e];
    atomicAdd(&deg[r * N_NODES + d], 1);
    int slot = atomicAdd(&cnt[d], 1);
    if (slot < CAP) ebuf[d * CAP + slot] = (r << 17) | s;
}

__global__ void inv_deg_k(const int* __restrict__ deg, float* __restrict__ invd) {
    int t = blockIdx.x * 256 + threadIdx.x;
    if (t < N_RELS * N_NODES) {
        int dv = deg[t]; if (dv < 1) dv = 1;
        invd[t] = 1.0f / (float)dv;
    }
}

// ---------------------------------------------------------------------------
// Y[N,1152] = bf16( X[N,128] @ BT^T )   (K = 128, single LDS stage)
// grid (ceil(N/128), 9), block 256 = 4 waves in 2x2, each wave 64x64 region
// ---------------------------------------------------------------------------
__global__ __launch_bounds__(256) void gemm_xw(
    const float* __restrict__ X, const unsigned short* __restrict__ BT,
    unsigned short* __restrict__ Y) {
    __shared__ short As[128 * 136];   // [m][k], pad 8 shorts -> 2-way LDS (free)
    __shared__ short Bs[128 * 136];   // [n][k]
    int t = threadIdx.x;
    int rowBase = blockIdx.x * 128;
    int colBase = blockIdx.y * 128;

    // stage A: f32 -> bf16
    for (int it = 0; it < 16; ++it) {
        int idx = t + it * 256;               // 4096 float4 units
        int row = idx >> 5, c4 = idx & 31;
        int grow = rowBase + row;
        float4 v = make_float4(0.f, 0.f, 0.f, 0.f);
        if (grow < N_NODES) v = *(const float4*)&X[grow * 128 + c4 * 4];
        short* p = &As[row * 136 + c4 * 4];
        p[0] = f2b(v.x); p[1] = f2b(v.y); p[2] = f2b(v.z); p[3] = f2b(v.w);
    }
    // stage B (already transposed in global): 16B chunks
    for (int it = 0; it < 8; ++it) {
        int idx = t + it * 256;               // 2048 chunks of 8 shorts
        int n = idx >> 4, c = idx & 15;
        *(int4*)&Bs[n * 136 + c * 8] = *(const int4*)&BT[(colBase + n) * 128 + c * 8];
    }
    __syncthreads();

    int w = t >> 6, lane = t & 63;
    int wr = w >> 1, wc = w & 1;
    int ml = lane & 15, quad = lane >> 4;
    f32x4 acc[4][4];
    for (int i = 0; i < 4; ++i)
        for (int j = 0; j < 4; ++j)
            acc[i][j] = (f32x4){0.f, 0.f, 0.f, 0.f};

    for (int kb = 0; kb < 4; ++kb) {
        int ko = kb * 32 + quad * 8;
        bf16x8 a[4], b[4];
        for (int i = 0; i < 4; ++i)
            a[i] = *(const bf16x8*)&As[(wr * 64 + i * 16 + ml) * 136 + ko];
        for (int j = 0; j < 4; ++j)
            b[j] = *(const bf16x8*)&Bs[(wc * 64 + j * 16 + ml) * 136 + ko];
        for (int i = 0; i < 4; ++i)
            for (int j = 0; j < 4; ++j)
                acc[i][j] = __builtin_amdgcn_mfma_f32_16x16x32_bf16(a[i], b[j], acc[i][j], 0, 0, 0);
    }

    // store: D[row=quad*4+rr][col=lane&15] per 16x16 tile
    for (int i = 0; i < 4; ++i) {
        for (int j = 0; j < 4; ++j) {
            int col = colBase + wc * 64 + j * 16 + ml;
            for (int rr = 0; rr < 4; ++rr) {
                int row = rowBase + wr * 64 + i * 16 + quad * 4 + rr;
                if (row < N_NODES)
                    Y[(long)row * KCOLS + col] = f2b(acc[i][j][rr]);
            }
        }
    }
}

// ---------------------------------------------------------------------------
// One wave per dst node: acc[128] (2 f32/lane) = sum over incoming edges of
// Y[src, r*128:+128] * inv_deg[r][dst]; + self cols + bias; relu; store f32.
// Edge records preloaded lane-parallel, broadcast via shuffle (no serial
// dependent loads in the loop).
// ---------------------------------------------------------------------------
__global__ __launch_bounds__(256) void agg(
    const unsigned short* __restrict__ Y, const int* __restrict__ ebuf,
    const int* __restrict__ cnt, const float* __restrict__ invd,
    const float* __restrict__ bias, float* __restrict__ out) {
    int d = (blockIdx.x << 2) + (threadIdx.x >> 6);
    if (d >= N_NODES) return;
    int lane = threadIdx.x & 63;

    int k = cnt[d]; if (k > CAP) k = CAP;
    int rec = 0; float wgt = 0.f;
    if (lane < k) {
        rec = ebuf[d * CAP + lane];
        wgt = invd[(rec >> 17) * N_NODES + d];
    }

    float ax = 0.f, ay = 0.f;
    for (int idx = 0; idx < k; ++idx) {
        int   rc = __shfl(rec, idx);
        float ww = __shfl(wgt, idx);
        int s = rc & 0x1FFFF;
        int r = rc >> 17;
        unsigned int y2 = *(const unsigned int*)&Y[(long)s * KCOLS + (r << 7) + (lane << 1)];
        ax += b2f((unsigned short)(y2 & 0xFFFF)) * ww;
        ay += b2f((unsigned short)(y2 >> 16)) * ww;
    }

    unsigned int sv = *(const unsigned int*)&Y[(long)d * KCOLS + 1024 + (lane << 1)];
    float ox = ax + b2f((unsigned short)(sv & 0xFFFF)) + bias[lane << 1];
    float oy = ay + b2f((unsigned short)(sv >> 16))    + bias[(lane << 1) + 1];
    ox = fmaxf(ox, 0.f);
    oy = fmaxf(oy, 0.f);
    *(float2*)&out[(long)d * 128 + (lane << 1)] = make_float2(ox, oy);
}

// ---------------------------------------------------------------------------
extern "C" void kernel_launch(void* const* d_in, const int* in_sizes, int n_in,
                              void* d_out, int out_size, void* d_ws, size_t ws_size,
                              hipStream_t stream) {
    const float* x     = (const float*)d_in[0];
    const float* W     = (const float*)d_in[1];
    const float* Wself = (const float*)d_in[2];
    const float* bias  = (const float*)d_in[3];
    const int*   src   = (const int*)d_in[4];
    const int*   dst   = (const int*)d_in[5];
    float* out = (float*)d_out;

    char* ws = (char*)d_ws;
    size_t off = 0;
    unsigned short* Y  = (unsigned short*)(ws + off); off += (size_t)N_NODES * KCOLS * 2;  // 230.4 MB
    unsigned short* BT = (unsigned short*)(ws + off); off += (size_t)KCOLS * 128 * 2;      // 0.3 MB
    int*   deg  = (int*)(ws + off);   off += (size_t)N_RELS * N_NODES * 4;                 // 3.2 MB
    float* invd = (float*)(ws + off); off += (size_t)N_RELS * N_NODES * 4;                 // 3.2 MB
    int*   cnt  = (int*)(ws + off);   off += (size_t)N_NODES * 4;                          // 0.4 MB
    int*   ebuf = (int*)(ws + off);   off += (size_t)N_NODES * CAP * 4;                    // 25.6 MB

    hipMemsetAsync(deg, 0, (size_t)N_RELS * N_NODES * 4, stream);
    hipMemsetAsync(cnt, 0, (size_t)N_NODES * 4, stream);

    prep_w<<<(KCOLS * 128 + 255) / 256, 256, 0, stream>>>(W, Wself, BT);

    dim3 eg((N_EDGES + 255) / 256, N_RELS);
    edge_build<<<eg, 256, 0, stream>>>(src, dst, deg, cnt, ebuf);

    inv_deg_k<<<(N_RELS * N_NODES + 255) / 256, 256, 0, stream>>>(deg, invd);

    dim3 gg((N_NODES + 127) / 128, KCOLS / 128);
    gemm_xw<<<gg, 256, 0, stream>>>(x, BT, Y);

    agg<<<(N_NODES + 3) / 4, 256, 0, stream>>>(Y, ebuf, cnt, invd, bias, out);
}

// Round 2
// 413.641 us; speedup vs baseline: 1.2063x; 1.2063x over previous
//
#include <hip/hip_runtime.h>
#include <hip/hip_bf16.h>
#include <stdint.h>

#define N_NODES 100000
#define N_RELS  8
#define N_EDGES 150000
#define KCOLS   1152   // K = 8*128 relation cols + 128 self-loop cols
#define CAP     64     // per-dst combined bucket capacity (avg deg = 12)

typedef short bf16x8 __attribute__((ext_vector_type(8)));
typedef float f32x4  __attribute__((ext_vector_type(4)));

__device__ __forceinline__ unsigned short f2b(float f) {
    union { float f; unsigned u; } v; v.f = f;
    unsigned r = v.u + 0x7FFF + ((v.u >> 16) & 1);   // RNE
    return (unsigned short)(r >> 16);
}
__device__ __forceinline__ float b2f(unsigned short h) {
    union { unsigned u; float f; } v; v.u = ((unsigned)h) << 16;
    return v.f;
}

// ---------------------------------------------------------------------------
// BT[n][k]  (n in [0,128) output col, k in [0,1152)): bf16 weight transpose.
// k<1024: W[r=k>>7, kk=k&127, n];  k>=1024: Wself[k-1024, n]
// ---------------------------------------------------------------------------
__global__ void prep_w(const float* __restrict__ W, const float* __restrict__ Wself,
                       unsigned short* __restrict__ BT) {
    int flat = blockIdx.x * 256 + threadIdx.x;
    if (flat >= 128 * KCOLS) return;
    int n = flat / KCOLS, k = flat - n * KCOLS;
    float v;
    if (k < 1024) {
        int r = k >> 7, kk = k & 127;
        v = W[(r << 14) + (kk << 7) + n];
    } else {
        v = Wself[((k - 1024) << 7) + n];
    }
    BT[flat] = f2b(v);
}

// x (f32) -> xb (bf16), 8 elems/thread
__global__ void cast_x(const float* __restrict__ X, unsigned short* __restrict__ xb) {
    int t = blockIdx.x * 256 + threadIdx.x;           // 1.6M threads
    if (t >= N_NODES * 16) return;
    const float4* p = (const float4*)(X + (size_t)t * 8);
    float4 a = p[0], b = p[1];
    unsigned short o[8] = { f2b(a.x), f2b(a.y), f2b(a.z), f2b(a.w),
                            f2b(b.x), f2b(b.y), f2b(b.z), f2b(b.w) };
    *(int4*)(xb + (size_t)t * 8) = *(const int4*)o;
}

// per-edge scatter into per-dst bucket; rec = (r<<17)|src
__global__ void edge_build(const int* __restrict__ src, const int* __restrict__ dst,
                           int* __restrict__ cnt, int* __restrict__ ebuf) {
    int e = blockIdx.x * 256 + threadIdx.x;
    int r = blockIdx.y;
    if (e >= N_EDGES) return;
    int s = src[r * N_EDGES + e];
    int d = dst[r * N_EDGES + e];
    int slot = atomicAdd(&cnt[d], 1);
    if (slot < CAP) ebuf[d * CAP + slot] = (r << 17) | s;
}

// ---------------------------------------------------------------------------
// One wave per dst: Agg[d, r*128:+128] = inv_deg_r * sum_{edges r->d} xb[src]
// Degrees recovered from the bucket itself via ballot/popcount.
// Always writes all 1024 cols (zeros where no edges) -> no memset of Agg.
// ---------------------------------------------------------------------------
__global__ __launch_bounds__(256) void agg_x(
    const unsigned short* __restrict__ xb, const int* __restrict__ ebuf,
    const int* __restrict__ cnt, unsigned short* __restrict__ Agg) {
    int d = (blockIdx.x << 2) + (threadIdx.x >> 6);
    if (d >= N_NODES) return;
    int lane = threadIdx.x & 63;

    int k = cnt[d]; if (k > CAP) k = CAP;
    int rec = (lane < k) ? ebuf[d * CAP + lane] : -1;
    int rl = rec >> 17;                    // -1 for idle lanes (no match)

    float inv[8];
#pragma unroll
    for (int r = 0; r < 8; ++r) {
        int dg = __popcll(__ballot(rl == r));
        inv[r] = 1.0f / (float)(dg < 1 ? 1 : dg);
    }

    float ax[8], ay[8];
#pragma unroll
    for (int r = 0; r < 8; ++r) { ax[r] = 0.f; ay[r] = 0.f; }

    for (int idx = 0; idx < k; ++idx) {
        int rc = __shfl(rec, idx);
        int s  = rc & 0x1FFFF;
        int r  = rc >> 17;
        unsigned int y2 = *(const unsigned int*)&xb[(size_t)s * 128 + (lane << 1)];
        float vx = b2f((unsigned short)(y2 & 0xFFFF));
        float vy = b2f((unsigned short)(y2 >> 16));
#pragma unroll
        for (int rr = 0; rr < 8; ++rr) {
            if (r == rr) { ax[rr] += vx; ay[rr] += vy; }
        }
    }

#pragma unroll
    for (int r = 0; r < 8; ++r) {
        unsigned short lo = f2b(ax[r] * inv[r]);
        unsigned short hi = f2b(ay[r] * inv[r]);
        unsigned int pk = (unsigned int)lo | ((unsigned int)hi << 16);
        *(unsigned int*)&Agg[(size_t)d * 1024 + (r << 7) + (lane << 1)] = pk;
    }
}

// ---------------------------------------------------------------------------
// out[N,128] f32 = relu( [Agg | xb][N,1152] @ BT^T + bias )
// 128x128 out tile/block, 4 waves 2x2, K-loop over 9 chunks of 128.
// ---------------------------------------------------------------------------
__global__ __launch_bounds__(256) void gemm_out(
    const unsigned short* __restrict__ Agg, const unsigned short* __restrict__ xb,
    const unsigned short* __restrict__ BT, const float* __restrict__ bias,
    float* __restrict__ out) {
    __shared__ short As[128 * 136];
    __shared__ short Bs[128 * 136];
    int t = threadIdx.x;
    int rowBase = blockIdx.x * 128;

    int w = t >> 6, lane = t & 63;
    int wr = w >> 1, wc = w & 1;
    int ml = lane & 15, quad = lane >> 4;

    f32x4 acc[4][4];
#pragma unroll
    for (int i = 0; i < 4; ++i)
#pragma unroll
        for (int j = 0; j < 4; ++j)
            acc[i][j] = (f32x4){0.f, 0.f, 0.f, 0.f};

    for (int kc = 0; kc < 9; ++kc) {
        // stage A chunk: rows [rowBase,+128), k cols [kc*128,+128)
#pragma unroll
        for (int it = 0; it < 8; ++it) {
            int idx = t + it * 256;            // 2048 int4 units
            int row = idx >> 4, c = idx & 15;
            int grow = rowBase + row;
            int4 v = make_int4(0, 0, 0, 0);
            if (grow < N_NODES) {
                if (kc < 8)
                    v = *(const int4*)&Agg[(size_t)grow * 1024 + (kc << 7) + c * 8];
                else
                    v = *(const int4*)&xb[(size_t)grow * 128 + c * 8];
            }
            *(int4*)&As[row * 136 + c * 8] = v;
        }
        // stage B chunk: BT[n][kc*128 + kk]
#pragma unroll
        for (int it = 0; it < 8; ++it) {
            int idx = t + it * 256;
            int n = idx >> 4, c = idx & 15;
            *(int4*)&Bs[n * 136 + c * 8] =
                *(const int4*)&BT[(size_t)n * KCOLS + (kc << 7) + c * 8];
        }
        __syncthreads();

#pragma unroll
        for (int kb = 0; kb < 4; ++kb) {
            int ko = kb * 32 + quad * 8;
            bf16x8 a[4], b[4];
#pragma unroll
            for (int i = 0; i < 4; ++i)
                a[i] = *(const bf16x8*)&As[(wr * 64 + i * 16 + ml) * 136 + ko];
#pragma unroll
            for (int j = 0; j < 4; ++j)
                b[j] = *(const bf16x8*)&Bs[(wc * 64 + j * 16 + ml) * 136 + ko];
#pragma unroll
            for (int i = 0; i < 4; ++i)
#pragma unroll
                for (int j = 0; j < 4; ++j)
                    acc[i][j] = __builtin_amdgcn_mfma_f32_16x16x32_bf16(a[i], b[j], acc[i][j], 0, 0, 0);
        }
        __syncthreads();
    }

    // epilogue: + bias, relu, f32 store
#pragma unroll
    for (int i = 0; i < 4; ++i) {
#pragma unroll
        for (int j = 0; j < 4; ++j) {
            int col = wc * 64 + j * 16 + ml;
            float bv = bias[col];
#pragma unroll
            for (int rr = 0; rr < 4; ++rr) {
                int row = rowBase + wr * 64 + i * 16 + quad * 4 + rr;
                if (row < N_NODES) {
                    float v = acc[i][j][rr] + bv;
                    out[(size_t)row * 128 + col] = fmaxf(v, 0.f);
                }
            }
        }
    }
}

// ---------------------------------------------------------------------------
extern "C" void kernel_launch(void* const* d_in, const int* in_sizes, int n_in,
                              void* d_out, int out_size, void* d_ws, size_t ws_size,
                              hipStream_t stream) {
    const float* x     = (const float*)d_in[0];
    const float* W     = (const float*)d_in[1];
    const float* Wself = (const float*)d_in[2];
    const float* bias  = (const float*)d_in[3];
    const int*   src   = (const int*)d_in[4];
    const int*   dst   = (const int*)d_in[5];
    float* out = (float*)d_out;

    char* ws = (char*)d_ws;
    size_t off = 0;
    unsigned short* Agg = (unsigned short*)(ws + off); off += (size_t)N_NODES * 1024 * 2; // 204.8 MB
    unsigned short* xb  = (unsigned short*)(ws + off); off += (size_t)N_NODES * 128 * 2;  // 25.6 MB
    unsigned short* BT  = (unsigned short*)(ws + off); off += (size_t)128 * KCOLS * 2;    // 0.3 MB
    int* cnt  = (int*)(ws + off); off += (size_t)N_NODES * 4;                             // 0.4 MB
    int* ebuf = (int*)(ws + off); off += (size_t)N_NODES * CAP * 4;                       // 25.6 MB

    hipMemsetAsync(cnt, 0, (size_t)N_NODES * 4, stream);

    prep_w<<<(128 * KCOLS + 255) / 256, 256, 0, stream>>>(W, Wself, BT);
    cast_x<<<(N_NODES * 16 + 255) / 256, 256, 0, stream>>>(x, xb);

    dim3 eg((N_EDGES + 255) / 256, N_RELS);
    edge_build<<<eg, 256, 0, stream>>>(src, dst, cnt, ebuf);

    agg_x<<<(N_NODES + 3) / 4, 256, 0, stream>>>(xb, ebuf, cnt, Agg);

    gemm_out<<<(N_NODES + 127) / 128, 256, 0, stream>>>(Agg, xb, BT, bias, out);
}